// Round 1
// baseline (630.066 us; speedup 1.0000x reference)
//
#include <hip/hip_runtime.h>
#include <hip/hip_bf16.h>
#include <stdint.h>

// Problem constants
#define B_   2
#define S_   2048
#define H_   2048
#define NH_  16
#define HD_  128
#define MTOK 4096      // B*S
#define NQKV 6144      // 3*H

typedef unsigned short u16;
typedef __attribute__((ext_vector_type(8))) __bf16 bf16x8;
typedef __attribute__((ext_vector_type(4))) float f32x4;

static __device__ __forceinline__ float bf2f(u16 u){
  union { uint32_t i; float f; } v; v.i = ((uint32_t)u) << 16; return v.f;
}
static __device__ __forceinline__ u16 f2bf(float f){
  union { float f; uint32_t i; } v; v.f = f;
  uint32_t r = v.i + 0x7FFFu + ((v.i >> 16) & 1u);   // RNE
  return (u16)(r >> 16);
}

__device__ __forceinline__ void gload_lds16(const void* g, void* l){
  __builtin_amdgcn_global_load_lds((const __attribute__((address_space(1))) void*)g,
                                   (__attribute__((address_space(3))) void*)l, 16, 0, 0);
}

// ---------- absmean (deterministic two-stage) ----------
__global__ void absum_kernel(const float* __restrict__ w, int n, float* __restrict__ partial){
  __shared__ float sm[256];
  float s = 0.f;
  for (int i = blockIdx.x*256 + threadIdx.x; i < n; i += gridDim.x*256)
    s += fabsf(w[i]);
  sm[threadIdx.x] = s; __syncthreads();
  for (int st = 128; st > 0; st >>= 1){
    if ((int)threadIdx.x < st) sm[threadIdx.x] += sm[threadIdx.x + st];
    __syncthreads();
  }
  if (threadIdx.x == 0) partial[blockIdx.x] = sm[0];
}

__global__ void finalize_kernel(const float* __restrict__ p1, const float* __restrict__ p2,
                                float* __restrict__ scales){
  __shared__ double sm[256];
  int t = threadIdx.x;
  double s = (double)p1[t] + (double)p1[t+256] + (double)p1[t+512] + (double)p1[t+768];
  sm[t] = s; __syncthreads();
  for (int st = 128; st > 0; st >>= 1){ if (t < st) sm[t] += sm[t+st]; __syncthreads(); }
  if (t == 0) scales[0] = (float)(1.0 / (sm[0] / (double)(3*H_*H_) + 1e-5));
  __syncthreads();
  s = (double)p2[t] + (double)p2[t+256] + (double)p2[t+512] + (double)p2[t+768];
  sm[t] = s; __syncthreads();
  for (int st = 128; st > 0; st >>= 1){ if (t < st) sm[t] += sm[t+st]; __syncthreads(); }
  if (t == 0) scales[1] = (float)(1.0 / (sm[0] / (double)(H_*H_) + 1e-5));
}

// ---------- ternary quantize to bf16 {-1,0,1} ----------
__global__ void quant_kernel(const float* __restrict__ w, u16* __restrict__ wq, int n,
                             const float* __restrict__ scales, int which){
  float inv = scales[which];
  for (int i = blockIdx.x*256 + threadIdx.x; i < n; i += gridDim.x*256){
    float q = rintf(w[i] * inv);            // rint = round-half-even, matches np.round
    q = fminf(1.f, fmaxf(-1.f, q));
    wq[i] = f2bf(q);
  }
}

__global__ void castx_kernel(const float* __restrict__ x, u16* __restrict__ xb, int n){
  int i = blockIdx.x*256 + threadIdx.x;
  if (i < n) xb[i] = f2bf(x[i]);
}

// ---------- GEMM C = A * B^T, 128x128 tile, BK=32, 4 waves (m97 structure) ----------
// EPI=0: qkv epilogue -> scatter to q[B,NH,S,HD], k[B,NH,S,HD], v^T[B,NH,HD,S] (bf16)
// EPI=1: proj epilogue -> fp32 out with clip(acc/16, +-128)
template<int EPI>
__global__ __launch_bounds__(256) void gemm_kernel(const u16* __restrict__ A,
    const u16* __restrict__ Bw, int M, int N, int K,
    float* __restrict__ outf, u16* __restrict__ qb, u16* __restrict__ kb, u16* __restrict__ vtb)
{
  __shared__ u16 As[128*32];
  __shared__ u16 Bs[128*32];
  int nbn = N >> 7;
  int nb_tot = (M >> 7) * nbn;
  int bid = blockIdx.x;
  int chunk = nb_tot >> 3;                 // grid always divisible by 8 here
  bid = (bid & 7) * chunk + (bid >> 3);    // XCD-contiguous swizzle (bijective)
  int bm = bid / nbn, bn = bid % nbn;
  int m0 = bm << 7, n0 = bn << 7;
  int tid = threadIdx.x;
  int lane = tid & 63, wid = tid >> 6;
  int wr = wid >> 1, wc = wid & 1;
  int lg = lane >> 4, lr = lane & 15;

  const u16* Ab = A + m0 * K;
  const u16* Bb = Bw + n0 * K;
  int srow = tid >> 2;
  int scol = (tid & 3) << 3;

  f32x4 acc[4][4];
  #pragma unroll
  for (int i = 0; i < 4; i++)
    #pragma unroll
    for (int j = 0; j < 4; j++) acc[i][j] = f32x4{0.f,0.f,0.f,0.f};

  for (int k0 = 0; k0 < K; k0 += 32){
    gload_lds16(Ab + srow*K      + k0 + scol, As + tid*8);
    gload_lds16(Ab + (srow+64)*K + k0 + scol, As + 2048 + tid*8);
    gload_lds16(Bb + srow*K      + k0 + scol, Bs + tid*8);
    gload_lds16(Bb + (srow+64)*K + k0 + scol, Bs + 2048 + tid*8);
    __syncthreads();
    bf16x8 af[4], bfr[4];
    #pragma unroll
    for (int mi = 0; mi < 4; mi++) af[mi]  = *(const bf16x8*)(As + ((wr*64 + mi*16 + lr)*32 + lg*8));
    #pragma unroll
    for (int ni = 0; ni < 4; ni++) bfr[ni] = *(const bf16x8*)(Bs + ((wc*64 + ni*16 + lr)*32 + lg*8));
    #pragma unroll
    for (int mi = 0; mi < 4; mi++)
      #pragma unroll
      for (int ni = 0; ni < 4; ni++)
        acc[mi][ni] = __builtin_amdgcn_mfma_f32_16x16x32_bf16(af[mi], bfr[ni], acc[mi][ni], 0, 0, 0);
    __syncthreads();
  }

  #pragma unroll
  for (int mi = 0; mi < 4; mi++){
    #pragma unroll
    for (int ni = 0; ni < 4; ni++){
      int ncol = n0 + wc*64 + ni*16 + lr;
      #pragma unroll
      for (int r = 0; r < 4; r++){
        int m = m0 + wr*64 + mi*16 + lg*4 + r;
        float v = acc[mi][ni][r] * 0.0625f;           // /16
        v = fminf(128.f, fmaxf(-128.f, v));
        if (EPI == 1){
          outf[m*N + ncol] = v;
        } else {
          int b = m >> 11, s = m & 2047;
          int part = ncol >> 11, c = ncol & 2047;
          int h = c >> 7, d = c & 127;
          int bh = b*NH_ + h;
          u16 bv = f2bf(v);
          if (part == 0)      qb[((bh*S_ + s) << 7) + d] = bv;
          else if (part == 1) kb[((bh*S_ + s) << 7) + d] = bv;
          else                vtb[((bh*HD_ + d) << 11) + s] = bv;  // V transposed
        }
      }
    }
  }
}

// ---------- RoPE in place on q,k [B*NH, S, HD] ----------
__global__ void rope_kernel(u16* __restrict__ qb, u16* __restrict__ kb, const float* __restrict__ rot){
  int i = blockIdx.x*256 + threadIdx.x;   // grid covers 2*32*2048*64 exactly
  int d = i & 63;
  int s = (i >> 6) & 2047;
  int bh = (i >> 17) & 31;
  u16* buf = (i >> 22) ? kb : qb;
  int base = (bh*S_ + s)*HD_;
  float c  = rot[s*HD_ + d];              // cos[d] == cos[d+64]
  float sn = rot[S_*HD_ + s*HD_ + d];
  float x1 = bf2f(buf[base + d]);
  float x2 = bf2f(buf[base + d + 64]);
  buf[base + d]      = f2bf(x1*c - x2*sn);
  buf[base + d + 64] = f2bf(x2*c + x1*sn);
}

// ---------- causal flash attention; 4 waves x 16 q-rows, KBLK=32 ----------
__global__ __launch_bounds__(256) void attn_kernel(const u16* __restrict__ qb,
    const u16* __restrict__ kb, const u16* __restrict__ vtb, u16* __restrict__ ao)
{
  __shared__ u16 P_lds[4][16*32];
  int nqt = S_ / 64;                        // 32
  int bid = blockIdx.x;
  int chunk = (32*nqt) >> 3;
  bid = (bid & 7) * chunk + (bid >> 3);     // XCD swizzle: keep heads contiguous per XCD
  int bh = bid / nqt, qt = bid % nqt;
  int tid = threadIdx.x;
  int wid = tid >> 6, lane = tid & 63;
  int lg = lane >> 4, lr = lane & 15;
  int qw = qt*64 + wid*16;

  const u16* Qp = qb + (bh*S_ + qw)*HD_;
  const u16* Kp = kb + bh*S_*HD_;
  const u16* Vt = vtb + bh*HD_*S_;

  bf16x8 qf[4];
  #pragma unroll
  for (int kk = 0; kk < 4; kk++) qf[kk] = *(const bf16x8*)(Qp + lr*HD_ + kk*32 + lg*8);

  f32x4 o[8];
  #pragma unroll
  for (int i = 0; i < 8; i++) o[i] = f32x4{0.f,0.f,0.f,0.f};
  float m_r[4], l_r[4];
  #pragma unroll
  for (int r = 0; r < 4; r++){ m_r[r] = -1e30f; l_r[r] = 0.f; }

  const float sm_scale = 0.08838834764831845f;  // 1/sqrt(128)
  int ktend = qw + 16;
  for (int kt = 0; kt < ktend; kt += 32){
    f32x4 s0 = f32x4{0.f,0.f,0.f,0.f}, s1 = f32x4{0.f,0.f,0.f,0.f};
    #pragma unroll
    for (int kk = 0; kk < 4; kk++){
      bf16x8 b0 = *(const bf16x8*)(Kp + (kt + lr)*HD_      + kk*32 + lg*8);
      bf16x8 b1 = *(const bf16x8*)(Kp + (kt + 16 + lr)*HD_ + kk*32 + lg*8);
      s0 = __builtin_amdgcn_mfma_f32_16x16x32_bf16(qf[kk], b0, s0, 0, 0, 0);
      s1 = __builtin_amdgcn_mfma_f32_16x16x32_bf16(qf[kk], b1, s1, 0, 0, 0);
    }
    float sv0[4], sv1[4], tmax[4];
    #pragma unroll
    for (int r = 0; r < 4; r++){
      int qglob = qw + lg*4 + r;
      sv0[r] = (kt + lr      > qglob) ? -1e30f : s0[r]*sm_scale;
      sv1[r] = (kt + 16 + lr > qglob) ? -1e30f : s1[r]*sm_scale;
      tmax[r] = fmaxf(sv0[r], sv1[r]);
    }
    #pragma unroll
    for (int off = 1; off < 16; off <<= 1){
      #pragma unroll
      for (int r = 0; r < 4; r++) tmax[r] = fmaxf(tmax[r], __shfl_xor(tmax[r], off));
    }
    float scl[4], p0[4], p1[4], ts[4];
    #pragma unroll
    for (int r = 0; r < 4; r++){
      float mn = fmaxf(m_r[r], tmax[r]);
      scl[r] = __expf(m_r[r] - mn);
      m_r[r] = mn;
      p0[r] = __expf(sv0[r] - mn);
      p1[r] = __expf(sv1[r] - mn);
      ts[r] = p0[r] + p1[r];
    }
    #pragma unroll
    for (int off = 1; off < 16; off <<= 1){
      #pragma unroll
      for (int r = 0; r < 4; r++) ts[r] += __shfl_xor(ts[r], off);
    }
    #pragma unroll
    for (int r = 0; r < 4; r++) l_r[r] = l_r[r]*scl[r] + ts[r];
    #pragma unroll
    for (int nb = 0; nb < 8; nb++)
      #pragma unroll
      for (int r = 0; r < 4; r++) o[nb][r] *= scl[r];

    // P (C-layout) -> LDS -> A-layout bf16 fragment
    u16* pl = P_lds[wid];
    #pragma unroll
    for (int r = 0; r < 4; r++){
      pl[(lg*4+r)*32 + lr]      = f2bf(p0[r]);
      pl[(lg*4+r)*32 + 16 + lr] = f2bf(p1[r]);
    }
    bf16x8 pf = *(const bf16x8*)(pl + lr*32 + lg*8);
    #pragma unroll
    for (int nb = 0; nb < 8; nb++){
      bf16x8 vf = *(const bf16x8*)(Vt + (nb*16 + lr)*S_ + kt + lg*8);
      o[nb] = __builtin_amdgcn_mfma_f32_16x16x32_bf16(pf, vf, o[nb], 0, 0, 0);
    }
  }

  int b = bh >> 4, h = bh & 15;
  #pragma unroll
  for (int r = 0; r < 4; r++){
    float inv = 1.f / l_r[r];
    int q = qw + lg*4 + r;
    u16* orow = ao + (b*S_ + q)*H_ + h*HD_;
    #pragma unroll
    for (int nb = 0; nb < 8; nb++)
      orow[nb*16 + lr] = f2bf(o[nb][r] * inv);
  }
}

extern "C" void kernel_launch(void* const* d_in, const int* in_sizes, int n_in,
                              void* d_out, int out_size, void* d_ws, size_t ws_size,
                              hipStream_t stream) {
  const float* x      = (const float*)d_in[0];
  const float* rotary = (const float*)d_in[1];
  const float* w_qkv  = (const float*)d_in[2];
  const float* w_o    = (const float*)d_in[3];
  float* out = (float*)d_out;

  char* wsb = (char*)d_ws;
  float* part_qkv = (float*)wsb;             // [1024]
  float* part_o   = part_qkv + 1024;         // [1024]
  float* scales   = part_o + 1024;           // [2]
  size_t off = 16384;
  u16* xb    = (u16*)(wsb + off); off += (size_t)MTOK*H_*2;
  u16* wqkvq = (u16*)(wsb + off); off += (size_t)NQKV*H_*2;
  u16* woq   = (u16*)(wsb + off); off += (size_t)H_*H_*2;
  u16* qbuf  = (u16*)(wsb + off); off += (size_t)B_*NH_*S_*HD_*2;
  u16* kbuf  = (u16*)(wsb + off); off += (size_t)B_*NH_*S_*HD_*2;
  u16* vtb   = (u16*)(wsb + off); off += (size_t)B_*NH_*S_*HD_*2;
  u16* ao    = (u16*)(wsb + off); off += (size_t)MTOK*H_*2;

  absum_kernel<<<1024, 256, 0, stream>>>(w_qkv, 3*H_*H_, part_qkv);
  absum_kernel<<<1024, 256, 0, stream>>>(w_o, H_*H_, part_o);
  finalize_kernel<<<1, 256, 0, stream>>>(part_qkv, part_o, scales);
  quant_kernel<<<4096, 256, 0, stream>>>(w_qkv, wqkvq, 3*H_*H_, scales, 0);
  quant_kernel<<<2048, 256, 0, stream>>>(w_o, woq, H_*H_, scales, 1);
  castx_kernel<<<(MTOK*H_)/256, 256, 0, stream>>>(x, xb, MTOK*H_);

  gemm_kernel<0><<<(MTOK/128)*(NQKV/128), 256, 0, stream>>>(xb, wqkvq, MTOK, NQKV, H_,
                                                            nullptr, qbuf, kbuf, vtb);
  rope_kernel<<<(2*B_*NH_*S_*64)/256, 256, 0, stream>>>(qbuf, kbuf, rotary);
  attn_kernel<<<B_*NH_*(S_/64), 256, 0, stream>>>(qbuf, kbuf, vtb, ao);
  gemm_kernel<1><<<(MTOK/128)*(H_/128), 256, 0, stream>>>(ao, woq, MTOK, H_, H_,
                                                          out, nullptr, nullptr, nullptr);
}

// Round 3
// 626.877 us; speedup vs baseline: 1.0051x; 1.0051x over previous
//
#include <hip/hip_runtime.h>
#include <hip/hip_bf16.h>
#include <stdint.h>

// Problem constants
#define B_   2
#define S_   2048
#define H_   2048
#define NH_  16
#define HD_  128
#define MTOK 4096      // B*S
#define NQKV 6144      // 3*H

typedef unsigned short u16;
typedef __attribute__((ext_vector_type(8))) __bf16 bf16x8;
typedef __attribute__((ext_vector_type(4))) float f32x4;

static __device__ __forceinline__ float bf2f(u16 u){
  union { uint32_t i; float f; } v; v.i = ((uint32_t)u) << 16; return v.f;
}
static __device__ __forceinline__ u16 f2bf(float f){
  union { float f; uint32_t i; } v; v.f = f;
  uint32_t r = v.i + 0x7FFFu + ((v.i >> 16) & 1u);   // RNE
  return (u16)(r >> 16);
}
static __device__ __forceinline__ uint32_t cvt_pk_bf16(float lo, float hi){
  uint32_t r;
  asm("v_cvt_pk_bf16_f32 %0, %1, %2" : "=v"(r) : "v"(lo), "v"(hi));
  return r;
}

__device__ __forceinline__ void gload_lds16(const void* g, void* l){
  __builtin_amdgcn_global_load_lds((const __attribute__((address_space(1))) void*)g,
                                   (__attribute__((address_space(3))) void*)l, 16, 0, 0);
}

// ---------- absmean (deterministic two-stage) ----------
__global__ void absum_kernel(const float* __restrict__ w, int n, float* __restrict__ partial){
  __shared__ float sm[256];
  float s = 0.f;
  for (int i = blockIdx.x*256 + threadIdx.x; i < n; i += gridDim.x*256)
    s += fabsf(w[i]);
  sm[threadIdx.x] = s; __syncthreads();
  for (int st = 128; st > 0; st >>= 1){
    if ((int)threadIdx.x < st) sm[threadIdx.x] += sm[threadIdx.x + st];
    __syncthreads();
  }
  if (threadIdx.x == 0) partial[blockIdx.x] = sm[0];
}

__global__ void finalize_kernel(const float* __restrict__ p1, const float* __restrict__ p2,
                                float* __restrict__ scales){
  __shared__ double sm[256];
  int t = threadIdx.x;
  double s = (double)p1[t] + (double)p1[t+256] + (double)p1[t+512] + (double)p1[t+768];
  sm[t] = s; __syncthreads();
  for (int st = 128; st > 0; st >>= 1){ if (t < st) sm[t] += sm[t+st]; __syncthreads(); }
  if (t == 0) scales[0] = (float)(1.0 / (sm[0] / (double)(3*H_*H_) + 1e-5));
  __syncthreads();
  s = (double)p2[t] + (double)p2[t+256] + (double)p2[t+512] + (double)p2[t+768];
  sm[t] = s; __syncthreads();
  for (int st = 128; st > 0; st >>= 1){ if (t < st) sm[t] += sm[t+st]; __syncthreads(); }
  if (t == 0) scales[1] = (float)(1.0 / (sm[0] / (double)(H_*H_) + 1e-5));
}

// ---------- ternary quantize to bf16 {-1,0,1} ----------
__global__ void quant_kernel(const float* __restrict__ w, u16* __restrict__ wq, int n,
                             const float* __restrict__ scales, int which){
  float inv = scales[which];
  for (int i = blockIdx.x*256 + threadIdx.x; i < n; i += gridDim.x*256){
    float q = rintf(w[i] * inv);
    q = fminf(1.f, fmaxf(-1.f, q));
    wq[i] = f2bf(q);
  }
}

__global__ void castx_kernel(const float* __restrict__ x, u16* __restrict__ xb, int n){
  int i = blockIdx.x*256 + threadIdx.x;
  if (i < n) xb[i] = f2bf(x[i]);
}

// ---------- GEMM C = A * B^T, 128x128 tile, BK=32, 4 waves (m97 structure) ----------
template<int EPI>
__global__ __launch_bounds__(256) void gemm_kernel(const u16* __restrict__ A,
    const u16* __restrict__ Bw, int M, int N, int K,
    float* __restrict__ outf, u16* __restrict__ qb, u16* __restrict__ kb, u16* __restrict__ vtb)
{
  __shared__ u16 As[128*32];
  __shared__ u16 Bs[128*32];
  int nbn = N >> 7;
  int nb_tot = (M >> 7) * nbn;
  int bid = blockIdx.x;
  int chunk = nb_tot >> 3;
  bid = (bid & 7) * chunk + (bid >> 3);    // XCD-contiguous swizzle (bijective)
  int bm = bid / nbn, bn = bid % nbn;
  int m0 = bm << 7, n0 = bn << 7;
  int tid = threadIdx.x;
  int lane = tid & 63, wid = tid >> 6;
  int wr = wid >> 1, wc = wid & 1;
  int lg = lane >> 4, lr = lane & 15;

  const u16* Ab = A + m0 * K;
  const u16* Bb = Bw + n0 * K;
  int srow = tid >> 2;
  int scol = (tid & 3) << 3;

  f32x4 acc[4][4];
  #pragma unroll
  for (int i = 0; i < 4; i++)
    #pragma unroll
    for (int j = 0; j < 4; j++) acc[i][j] = f32x4{0.f,0.f,0.f,0.f};

  for (int k0 = 0; k0 < K; k0 += 32){
    gload_lds16(Ab + srow*K      + k0 + scol, As + tid*8);
    gload_lds16(Ab + (srow+64)*K + k0 + scol, As + 2048 + tid*8);
    gload_lds16(Bb + srow*K      + k0 + scol, Bs + tid*8);
    gload_lds16(Bb + (srow+64)*K + k0 + scol, Bs + 2048 + tid*8);
    __syncthreads();
    bf16x8 af[4], bfr[4];
    #pragma unroll
    for (int mi = 0; mi < 4; mi++) af[mi]  = *(const bf16x8*)(As + ((wr*64 + mi*16 + lr)*32 + lg*8));
    #pragma unroll
    for (int ni = 0; ni < 4; ni++) bfr[ni] = *(const bf16x8*)(Bs + ((wc*64 + ni*16 + lr)*32 + lg*8));
    #pragma unroll
    for (int mi = 0; mi < 4; mi++)
      #pragma unroll
      for (int ni = 0; ni < 4; ni++)
        acc[mi][ni] = __builtin_amdgcn_mfma_f32_16x16x32_bf16(af[mi], bfr[ni], acc[mi][ni], 0, 0, 0);
    __syncthreads();
  }

  #pragma unroll
  for (int mi = 0; mi < 4; mi++){
    #pragma unroll
    for (int ni = 0; ni < 4; ni++){
      int ncol = n0 + wc*64 + ni*16 + lr;
      #pragma unroll
      for (int r = 0; r < 4; r++){
        int m = m0 + wr*64 + mi*16 + lg*4 + r;
        float v = acc[mi][ni][r] * 0.0625f;           // /16
        v = fminf(128.f, fmaxf(-128.f, v));
        if (EPI == 1){
          outf[m*N + ncol] = v;
        } else {
          int b = m >> 11, s = m & 2047;
          int part = ncol >> 11, c = ncol & 2047;
          int h = c >> 7, d = c & 127;
          int bh = b*NH_ + h;
          u16 bv = f2bf(v);
          if (part == 0)      qb[((bh*S_ + s) << 7) + d] = bv;
          else if (part == 1) kb[((bh*S_ + s) << 7) + d] = bv;
          else                vtb[((bh*HD_ + d) << 11) + s] = bv;  // V transposed
        }
      }
    }
  }
}

// ---------- RoPE in place on q,k [B*NH, S, HD] ----------
__global__ void rope_kernel(u16* __restrict__ qb, u16* __restrict__ kb, const float* __restrict__ rot){
  int i = blockIdx.x*256 + threadIdx.x;
  int d = i & 63;
  int s = (i >> 6) & 2047;
  int bh = (i >> 17) & 31;
  u16* buf = (i >> 22) ? kb : qb;
  int base = (bh*S_ + s)*HD_;
  float c  = rot[s*HD_ + d];
  float sn = rot[S_*HD_ + s*HD_ + d];
  float x1 = bf2f(buf[base + d]);
  float x2 = bf2f(buf[base + d + 64]);
  buf[base + d]      = f2bf(x1*c - x2*sn);
  buf[base + d + 64] = f2bf(x2*c + x1*sn);
}

// ---------- causal flash attention, swapped-operand (S^T) form ----------
// 4 waves/block, each wave owns 16 q rows (q = qw + lane&15).
// QK^T: mfma(K_frag, Q_frag) -> S^T: lane(lr,lg) holds keys {kt+4lg+r} and
// {kt+16+4lg+r} for q=qw+lr. Softmax per-lane + 2 shfl steps (xor16/xor32).
// P redistribution to PV B-frag via cvt_pk + 4 independent shfls.
// PV: mfma(Vt_frag, P_frag) -> O^T accumulated per 16-d block.
__global__ __launch_bounds__(256) void attn_kernel(const u16* __restrict__ qb,
    const u16* __restrict__ kb, const u16* __restrict__ vtb, u16* __restrict__ ao)
{
  int nqt = S_ / 64;                        // 32 q-tiles per head
  int bid = blockIdx.x;
  int chunk = (32*nqt) >> 3;                // 128 blocks per XCD
  bid = (bid & 7) * chunk + (bid >> 3);     // XCD swizzle: 4 heads contiguous per XCD
  int bh = bid / nqt;
  int qt = (nqt - 1) - (bid % nqt);         // longest blocks dispatch first
  int tid = threadIdx.x;
  int wid = tid >> 6, lane = tid & 63;
  int lg = lane >> 4, lr = lane & 15;
  int qw = qt*64 + wid*16;
  int q  = qw + lr;                         // this lane's q row

  const u16* Qp = qb + (bh*S_ + qw)*HD_;
  const u16* Kp = kb + bh*S_*HD_;
  const u16* Vt = vtb + bh*HD_*S_;

  bf16x8 qf[4];
  #pragma unroll
  for (int kk = 0; kk < 4; kk++) qf[kk] = *(const bf16x8*)(Qp + lr*HD_ + kk*32 + lg*8);

  f32x4 o[8];
  #pragma unroll
  for (int i = 0; i < 8; i++) o[i] = f32x4{0.f,0.f,0.f,0.f};
  float m_r = -1e30f, l_r = 0.f;
  const float sm_scale = 0.08838834764831845f;  // 1/sqrt(128)

  int nfull = qw >> 5;                      // unmasked 32-key tiles
  int srcA = ((((lg&1)<<1) | (lg>>1)) << 4) + lr;   // shfl source for rounds 0,2
  int srcB = srcA ^ 16;                              // rounds 1,3

  int kt = 0;
  for (int it = 0; it < nfull + 1; ++it, kt += 32){
    // ---- loads (V early so latency hides under QK+softmax) ----
    bf16x8 ka[4], kb2[4], vf[8];
    #pragma unroll
    for (int kk = 0; kk < 4; kk++){
      ka[kk]  = *(const bf16x8*)(Kp + (kt + lr)*HD_      + kk*32 + lg*8);
      kb2[kk] = *(const bf16x8*)(Kp + (kt + 16 + lr)*HD_ + kk*32 + lg*8);
    }
    #pragma unroll
    for (int db = 0; db < 8; db++)
      vf[db] = *(const bf16x8*)(Vt + (db*16 + lr)*S_ + kt + lg*8);

    // ---- QK^T (swapped): S^T[key][q] ----
    f32x4 s0 = f32x4{0.f,0.f,0.f,0.f}, s1 = f32x4{0.f,0.f,0.f,0.f};
    #pragma unroll
    for (int kk = 0; kk < 4; kk++){
      s0 = __builtin_amdgcn_mfma_f32_16x16x32_bf16(ka[kk],  qf[kk], s0, 0, 0, 0);
      s1 = __builtin_amdgcn_mfma_f32_16x16x32_bf16(kb2[kk], qf[kk], s1, 0, 0, 0);
    }

    float sv[8];
    if (it < nfull){                        // no masking needed
      #pragma unroll
      for (int r = 0; r < 4; r++){ sv[r] = s0[r]*sm_scale; sv[4+r] = s1[r]*sm_scale; }
    } else {                                // single masked tail tile
      #pragma unroll
      for (int r = 0; r < 4; r++){
        sv[r]   = (kt + 4*lg + r      > q) ? -1e30f : s0[r]*sm_scale;
        sv[4+r] = (kt + 16 + 4*lg + r > q) ? -1e30f : s1[r]*sm_scale;
      }
    }

    // ---- online softmax: in-lane over 8, then xor16+xor32 ----
    float pm = fmaxf(fmaxf(fmaxf(sv[0],sv[1]), fmaxf(sv[2],sv[3])),
                     fmaxf(fmaxf(sv[4],sv[5]), fmaxf(sv[6],sv[7])));
    pm = fmaxf(pm, __shfl_xor(pm, 16));
    pm = fmaxf(pm, __shfl_xor(pm, 32));
    float mn  = fmaxf(m_r, pm);
    float scl = __expf(m_r - mn);
    m_r = mn;
    float p[8];
    #pragma unroll
    for (int i = 0; i < 8; i++) p[i] = __expf(sv[i] - mn);
    float ts = ((p[0]+p[1]) + (p[2]+p[3])) + ((p[4]+p[5]) + (p[6]+p[7]));
    ts += __shfl_xor(ts, 16);
    ts += __shfl_xor(ts, 32);
    l_r = l_r*scl + ts;
    #pragma unroll
    for (int db = 0; db < 8; db++) o[db] *= scl;

    // ---- P -> bf16 B-frag redistribution (4-lane x 4-word permutation) ----
    uint32_t w0 = cvt_pk_bf16(p[0], p[1]);   // keys (4lg,   4lg+1)
    uint32_t w1 = cvt_pk_bf16(p[2], p[3]);   // keys (4lg+2, 4lg+3)
    uint32_t w2 = cvt_pk_bf16(p[4], p[5]);   // keys (16+4lg,   16+4lg+1)
    uint32_t w3 = cvt_pk_bf16(p[6], p[7]);   // keys (16+4lg+2, 16+4lg+3)
    uint32_t e0 = (lg & 1) ? w2 : w0;
    uint32_t e1 = (lg & 1) ? w0 : w2;
    uint32_t e2 = (lg & 1) ? w3 : w1;
    uint32_t e3 = (lg & 1) ? w1 : w3;
    uint32_t r0 = (uint32_t)__shfl((int)e0, srcA, 64);
    uint32_t r1 = (uint32_t)__shfl((int)e1, srcB, 64);
    uint32_t r2 = (uint32_t)__shfl((int)e2, srcA, 64);
    uint32_t r3 = (uint32_t)__shfl((int)e3, srcB, 64);
    union { uint32_t u[4]; bf16x8 v; } pu;
    pu.u[0] = (lg < 2) ? r0 : r1;
    pu.u[1] = (lg < 2) ? r2 : r3;
    pu.u[2] = (lg < 2) ? r1 : r0;
    pu.u[3] = (lg < 2) ? r3 : r2;

    // ---- PV (swapped): O^T[d][q] += V^T[d][k] * P[k][q] ----
    #pragma unroll
    for (int db = 0; db < 8; db++)
      o[db] = __builtin_amdgcn_mfma_f32_16x16x32_bf16(vf[db], pu.v, o[db], 0, 0, 0);
  }

  // ---- epilogue: lane(lr,lg) holds d = db*16 + 4lg + r for q = qw+lr ----
  float inv = 1.f / l_r;
  int b = bh >> 4, h = bh & 15;
  u16* orow = ao + ((size_t)(b*S_ + q))*H_ + h*HD_;
  #pragma unroll
  for (int db = 0; db < 8; db++){
    ushort4 pk;
    pk.x = f2bf(o[db][0]*inv);
    pk.y = f2bf(o[db][1]*inv);
    pk.z = f2bf(o[db][2]*inv);
    pk.w = f2bf(o[db][3]*inv);
    *(ushort4*)(orow + db*16 + lg*4) = pk;
  }
}

extern "C" void kernel_launch(void* const* d_in, const int* in_sizes, int n_in,
                              void* d_out, int out_size, void* d_ws, size_t ws_size,
                              hipStream_t stream) {
  const float* x      = (const float*)d_in[0];
  const float* rotary = (const float*)d_in[1];
  const float* w_qkv  = (const float*)d_in[2];
  const float* w_o    = (const float*)d_in[3];
  float* out = (float*)d_out;

  char* wsb = (char*)d_ws;
  float* part_qkv = (float*)wsb;             // [1024]
  float* part_o   = part_qkv + 1024;         // [1024]
  float* scales   = part_o + 1024;           // [2]
  size_t off = 16384;
  u16* xb    = (u16*)(wsb + off); off += (size_t)MTOK*H_*2;
  u16* wqkvq = (u16*)(wsb + off); off += (size_t)NQKV*H_*2;
  u16* woq   = (u16*)(wsb + off); off += (size_t)H_*H_*2;
  u16* qbuf  = (u16*)(wsb + off); off += (size_t)B_*NH_*S_*HD_*2;
  u16* kbuf  = (u16*)(wsb + off); off += (size_t)B_*NH_*S_*HD_*2;
  u16* vtb   = (u16*)(wsb + off); off += (size_t)B_*NH_*S_*HD_*2;
  u16* ao    = (u16*)(wsb + off); off += (size_t)MTOK*H_*2;

  absum_kernel<<<1024, 256, 0, stream>>>(w_qkv, 3*H_*H_, part_qkv);
  absum_kernel<<<1024, 256, 0, stream>>>(w_o, H_*H_, part_o);
  finalize_kernel<<<1, 256, 0, stream>>>(part_qkv, part_o, scales);
  quant_kernel<<<4096, 256, 0, stream>>>(w_qkv, wqkvq, 3*H_*H_, scales, 0);
  quant_kernel<<<2048, 256, 0, stream>>>(w_o, woq, H_*H_, scales, 1);
  castx_kernel<<<(MTOK*H_)/256, 256, 0, stream>>>(x, xb, MTOK*H_);

  gemm_kernel<0><<<(MTOK/128)*(NQKV/128), 256, 0, stream>>>(xb, wqkvq, MTOK, NQKV, H_,
                                                            nullptr, qbuf, kbuf, vtb);
  rope_kernel<<<(2*B_*NH_*S_*64)/256, 256, 0, stream>>>(qbuf, kbuf, rotary);
  attn_kernel<<<B_*NH_*(S_/64), 256, 0, stream>>>(qbuf, kbuf, vtb, ao);
  gemm_kernel<1><<<(MTOK/128)*(H_/128), 256, 0, stream>>>(ao, woq, MTOK, H_, H_,
                                                          out, nullptr, nullptr, nullptr);
}

// Round 4
// 400.512 us; speedup vs baseline: 1.5732x; 1.5652x over previous
//
#include <hip/hip_runtime.h>
#include <hip/hip_bf16.h>
#include <stdint.h>

// Problem constants
#define B_   2
#define S_   2048
#define H_   2048
#define NH_  16
#define HD_  128
#define MTOK 4096      // B*S
#define NQKV 6144      // 3*H

typedef unsigned short u16;
typedef __attribute__((ext_vector_type(8))) __bf16 bf16x8;
typedef __attribute__((ext_vector_type(4))) float f32x4;
typedef __attribute__((ext_vector_type(16))) float f32x16;

static __device__ __forceinline__ float bf2f(u16 u){
  union { uint32_t i; float f; } v; v.i = ((uint32_t)u) << 16; return v.f;
}
static __device__ __forceinline__ u16 f2bf(float f){
  union { float f; uint32_t i; } v; v.f = f;
  uint32_t r = v.i + 0x7FFFu + ((v.i >> 16) & 1u);   // RNE
  return (u16)(r >> 16);
}
static __device__ __forceinline__ uint32_t cvt_pk_bf16(float lo, float hi){
  uint32_t r;
  asm("v_cvt_pk_bf16_f32 %0, %1, %2" : "=v"(r) : "v"(lo), "v"(hi));
  return r;
}
static __device__ __forceinline__ void pl32swap(uint32_t &a, uint32_t &b){
  // a' = {a.lo32lanes, b.lo32lanes}; b' = {a.hi32lanes, b.hi32lanes}
  asm volatile("v_permlane32_swap_b32 %0, %1" : "+v"(a), "+v"(b));
}

__device__ __forceinline__ void gload_lds16(const void* g, void* l){
  __builtin_amdgcn_global_load_lds((const __attribute__((address_space(1))) void*)g,
                                   (__attribute__((address_space(3))) void*)l, 16, 0, 0);
}

// ---------- absmean (deterministic two-stage) ----------
__global__ void absum_kernel(const float* __restrict__ w, int n, float* __restrict__ partial){
  __shared__ float sm[256];
  float s = 0.f;
  for (int i = blockIdx.x*256 + threadIdx.x; i < n; i += gridDim.x*256)
    s += fabsf(w[i]);
  sm[threadIdx.x] = s; __syncthreads();
  for (int st = 128; st > 0; st >>= 1){
    if ((int)threadIdx.x < st) sm[threadIdx.x] += sm[threadIdx.x + st];
    __syncthreads();
  }
  if (threadIdx.x == 0) partial[blockIdx.x] = sm[0];
}

__global__ void finalize_kernel(const float* __restrict__ p1, const float* __restrict__ p2,
                                float* __restrict__ scales){
  __shared__ double sm[256];
  int t = threadIdx.x;
  double s = (double)p1[t] + (double)p1[t+256] + (double)p1[t+512] + (double)p1[t+768];
  sm[t] = s; __syncthreads();
  for (int st = 128; st > 0; st >>= 1){ if (t < st) sm[t] += sm[t+st]; __syncthreads(); }
  if (t == 0) scales[0] = (float)(1.0 / (sm[0] / (double)(3*H_*H_) + 1e-5));
  __syncthreads();
  s = (double)p2[t] + (double)p2[t+256] + (double)p2[t+512] + (double)p2[t+768];
  sm[t] = s; __syncthreads();
  for (int st = 128; st > 0; st >>= 1){ if (t < st) sm[t] += sm[t+st]; __syncthreads(); }
  if (t == 0) scales[1] = (float)(1.0 / (sm[0] / (double)(H_*H_) + 1e-5));
}

// ---------- ternary quantize to bf16 {-1,0,1} ----------
__global__ void quant_kernel(const float* __restrict__ w, u16* __restrict__ wq, int n,
                             const float* __restrict__ scales, int which){
  float inv = scales[which];
  for (int i = blockIdx.x*256 + threadIdx.x; i < n; i += gridDim.x*256){
    float q = rintf(w[i] * inv);
    q = fminf(1.f, fmaxf(-1.f, q));
    wq[i] = f2bf(q);
  }
}

__global__ void castx_kernel(const float* __restrict__ x, u16* __restrict__ xb, int n){
  int i = blockIdx.x*256 + threadIdx.x;
  if (i < n) xb[i] = f2bf(x[i]);
}

// ---------- GEMM C = A * B^T, 128x128 tile, BK=32, 4 waves (m97 structure) ----------
template<int EPI>
__global__ __launch_bounds__(256) void gemm_kernel(const u16* __restrict__ A,
    const u16* __restrict__ Bw, int M, int N, int K,
    float* __restrict__ outf, u16* __restrict__ qb, u16* __restrict__ kb, u16* __restrict__ vtb)
{
  __shared__ u16 As[128*32];
  __shared__ u16 Bs[128*32];
  int nbn = N >> 7;
  int nb_tot = (M >> 7) * nbn;
  int bid = blockIdx.x;
  int chunk = nb_tot >> 3;
  bid = (bid & 7) * chunk + (bid >> 3);    // XCD-contiguous swizzle (bijective)
  int bm = bid / nbn, bn = bid % nbn;
  int m0 = bm << 7, n0 = bn << 7;
  int tid = threadIdx.x;
  int lane = tid & 63, wid = tid >> 6;
  int wr = wid >> 1, wc = wid & 1;
  int lg = lane >> 4, lr = lane & 15;

  const u16* Ab = A + m0 * K;
  const u16* Bb = Bw + n0 * K;
  int srow = tid >> 2;
  int scol = (tid & 3) << 3;

  f32x4 acc[4][4];
  #pragma unroll
  for (int i = 0; i < 4; i++)
    #pragma unroll
    for (int j = 0; j < 4; j++) acc[i][j] = f32x4{0.f,0.f,0.f,0.f};

  for (int k0 = 0; k0 < K; k0 += 32){
    gload_lds16(Ab + srow*K      + k0 + scol, As + tid*8);
    gload_lds16(Ab + (srow+64)*K + k0 + scol, As + 2048 + tid*8);
    gload_lds16(Bb + srow*K      + k0 + scol, Bs + tid*8);
    gload_lds16(Bb + (srow+64)*K + k0 + scol, Bs + 2048 + tid*8);
    __syncthreads();
    bf16x8 af[4], bfr[4];
    #pragma unroll
    for (int mi = 0; mi < 4; mi++) af[mi]  = *(const bf16x8*)(As + ((wr*64 + mi*16 + lr)*32 + lg*8));
    #pragma unroll
    for (int ni = 0; ni < 4; ni++) bfr[ni] = *(const bf16x8*)(Bs + ((wc*64 + ni*16 + lr)*32 + lg*8));
    #pragma unroll
    for (int mi = 0; mi < 4; mi++)
      #pragma unroll
      for (int ni = 0; ni < 4; ni++)
        acc[mi][ni] = __builtin_amdgcn_mfma_f32_16x16x32_bf16(af[mi], bfr[ni], acc[mi][ni], 0, 0, 0);
    __syncthreads();
  }

  #pragma unroll
  for (int mi = 0; mi < 4; mi++){
    #pragma unroll
    for (int ni = 0; ni < 4; ni++){
      int ncol = n0 + wc*64 + ni*16 + lr;
      #pragma unroll
      for (int r = 0; r < 4; r++){
        int m = m0 + wr*64 + mi*16 + lg*4 + r;
        float v = acc[mi][ni][r] * 0.0625f;           // /16
        v = fminf(128.f, fmaxf(-128.f, v));
        if (EPI == 1){
          outf[m*N + ncol] = v;
        } else {
          int b = m >> 11, s = m & 2047;
          int part = ncol >> 11, c = ncol & 2047;
          int h = c >> 7, d = c & 127;
          int bh = b*NH_ + h;
          u16 bv = f2bf(v);
          if (part == 0)      qb[((bh*S_ + s) << 7) + d] = bv;
          else if (part == 1) kb[((bh*S_ + s) << 7) + d] = bv;
          else                vtb[((bh*HD_ + d) << 11) + s] = bv;  // V transposed
        }
      }
    }
  }
}

// ---------- RoPE in place on q,k [B*NH, S, HD] ----------
__global__ void rope_kernel(u16* __restrict__ qb, u16* __restrict__ kb, const float* __restrict__ rot){
  int i = blockIdx.x*256 + threadIdx.x;
  int d = i & 63;
  int s = (i >> 6) & 2047;
  int bh = (i >> 17) & 31;
  u16* buf = (i >> 22) ? kb : qb;
  int base = (bh*S_ + s)*HD_;
  float c  = rot[s*HD_ + d];
  float sn = rot[S_*HD_ + s*HD_ + d];
  float x1 = bf2f(buf[base + d]);
  float x2 = bf2f(buf[base + d + 64]);
  buf[base + d]      = f2bf(x1*c - x2*sn);
  buf[base + d + 64] = f2bf(x2*c + x1*sn);
}

// ---------- causal flash attention: 4 waves x 32 q-rows, 32x32x16 MFMA ----------
// K/V staged in LDS (frag-ordered, conflict-free), double-buffered with
// counted vmcnt(4) + raw barriers (T3/T4). Swapped QK^T (S^T = K·Q^T) keeps
// softmax lane-local; P->PV B-frag via cvt_pk + permlane32_swap (T12).
// C/D 32x32 layout: col = lane&31, row = (reg&3) + 8*(reg>>2) + 4*(lane>>5).
__global__ __launch_bounds__(256) void attn_kernel(const u16* __restrict__ qb,
    const u16* __restrict__ kb, const u16* __restrict__ vtb, u16* __restrict__ ao)
{
  __shared__ alignas(16) u16 Ks[2][4096];   // [buf][8 kd-sub][64 lane][8 bf16]
  __shared__ alignas(16) u16 Vs[2][4096];   // [buf][2 ks][4 db][64 lane][8 bf16]

  int bid = blockIdx.x;                     // 512 blocks
  int sbid = (bid & 7)*64 + (bid >> 3);     // XCD swizzle: 4 heads per XCD chunk
  int bh = sbid >> 4;
  int bq = 15 - (sbid & 15);                // longest q-blocks dispatch first
  int tid = threadIdx.x;
  int wid = tid >> 6, lane = tid & 63;
  int l31 = lane & 31, hl = lane >> 5;
  int q0 = bq * 128;
  int qw = q0 + wid*32;
  int q  = qw + l31;                        // this lane's q row

  const u16* Qp = qb + (size_t)(bh*S_ + qw)*HD_;
  const u16* Kp = kb + (size_t)bh*S_*HD_;
  const u16* Vt = vtb + (size_t)bh*HD_*S_;

  // Q B-frags: lane holds Q[q][t*16 + hl*8 .. +8]
  bf16x8 qf[8];
  #pragma unroll
  for (int t = 0; t < 8; t++)
    qf[t] = *(const bf16x8*)(Qp + l31*HD_ + t*16 + hl*8);

  f32x16 o[4];
  #pragma unroll
  for (int i = 0; i < 4; i++)
    #pragma unroll
    for (int j = 0; j < 16; j++) o[i][j] = 0.f;
  float m_r = -1e30f, l_r = 0.f;
  const float sm_scale = 0.08838834764831845f;  // 1/sqrt(128)

  // stage one 32-key K tile + V tile into buf (4 gload_lds per wave)
  auto STAGE = [&](int buf, int kt2){
    int t0 = wid*2;
    gload_lds16(Kp + (size_t)(kt2 + l31)*HD_ + (t0  )*16 + hl*8, &Ks[buf][((t0  )*64 + lane)*8]);
    gload_lds16(Kp + (size_t)(kt2 + l31)*HD_ + (t0+1)*16 + hl*8, &Ks[buf][((t0+1)*64 + lane)*8]);
    int v0 = wid*2, v1 = wid*2 + 1;
    gload_lds16(Vt + (size_t)((v0&3)*32 + l31)*S_ + kt2 + (v0>>2)*16 + hl*8, &Vs[buf][(v0*64 + lane)*8]);
    gload_lds16(Vt + (size_t)((v1&3)*32 + l31)*S_ + kt2 + (v1>>2)*16 + hl*8, &Vs[buf][(v1*64 + lane)*8]);
  };

  int n_it = 4*bq + 4;
  STAGE(0, 0);
  int cur = 0, kt = 0;
  for (int it = 0; it < n_it; ++it, kt += 32){
    if (it + 1 < n_it){
      STAGE(cur ^ 1, kt + 32);
      asm volatile("s_waitcnt vmcnt(4)" ::: "memory");   // drain cur's stage, keep next in flight
    } else {
      asm volatile("s_waitcnt vmcnt(0)" ::: "memory");
    }
    __builtin_amdgcn_sched_barrier(0);
    __builtin_amdgcn_s_barrier();

    if (kt <= qw){                          // not fully masked for this wave
      // ---- QK^T (swapped): S^T[key][q], keys kt..kt+31 ----
      f32x16 sa;
      #pragma unroll
      for (int j = 0; j < 16; j++) sa[j] = 0.f;
      #pragma unroll
      for (int t = 0; t < 8; t++){
        bf16x8 kf = *(const bf16x8*)(&Ks[cur][(t*64 + lane)*8]);
        sa = __builtin_amdgcn_mfma_f32_32x32x16_bf16(kf, qf[t], sa, 0, 0, 0);
      }

      float sv[16];
      if (kt == qw){                        // the single partial tile for this wave
        #pragma unroll
        for (int r = 0; r < 16; r++){
          int key = kt + (r&3) + 8*(r>>2) + 4*hl;
          sv[r] = (key > q) ? -1e30f : sa[r]*sm_scale;
        }
      } else {
        #pragma unroll
        for (int r = 0; r < 16; r++) sv[r] = sa[r]*sm_scale;
      }

      // ---- online softmax, lane-local + one cross-half max/sum ----
      float pm = sv[0];
      #pragma unroll
      for (int r = 1; r < 16; r++) pm = fmaxf(pm, sv[r]);
      pm = fmaxf(pm, __shfl_xor(pm, 32));
      if (!__all(pm - m_r <= 8.f)){         // defer-max (T13)
        float mn = fmaxf(m_r, pm);
        float scl = __expf(m_r - mn);
        m_r = mn; l_r *= scl;
        #pragma unroll
        for (int i = 0; i < 4; i++)
          #pragma unroll
          for (int j = 0; j < 16; j++) o[i][j] *= scl;
      }
      float p[16];
      #pragma unroll
      for (int r = 0; r < 16; r++) p[r] = __expf(sv[r] - m_r);
      float ts = 0.f;
      #pragma unroll
      for (int r = 0; r < 16; r++) ts += p[r];
      ts += __shfl_xor(ts, 32);
      l_r += ts;

      // ---- P -> PV B-frags via cvt_pk + permlane32_swap ----
      uint32_t a0 = cvt_pk_bf16(p[0],  p[1]),  a1 = cvt_pk_bf16(p[2],  p[3]);
      uint32_t a2 = cvt_pk_bf16(p[4],  p[5]),  a3 = cvt_pk_bf16(p[6],  p[7]);
      uint32_t b0 = cvt_pk_bf16(p[8],  p[9]),  b1 = cvt_pk_bf16(p[10], p[11]);
      uint32_t b2 = cvt_pk_bf16(p[12], p[13]), b3 = cvt_pk_bf16(p[14], p[15]);
      pl32swap(a0, a2); pl32swap(a1, a3);     // -> frag ks=0: [a0,a1,a2,a3]
      pl32swap(b0, b2); pl32swap(b1, b3);     // -> frag ks=1: [b0,b1,b2,b3]
      union { uint32_t u[4]; bf16x8 v; } pf0, pf1;
      pf0.u[0]=a0; pf0.u[1]=a1; pf0.u[2]=a2; pf0.u[3]=a3;
      pf1.u[0]=b0; pf1.u[1]=b1; pf1.u[2]=b2; pf1.u[3]=b3;

      // ---- PV (swapped): O^T[d][q] += V^T[d][k]*P[k][q] ----
      #pragma unroll
      for (int db = 0; db < 4; db++){
        bf16x8 vf0 = *(const bf16x8*)(&Vs[cur][((0*4 + db)*64 + lane)*8]);
        o[db] = __builtin_amdgcn_mfma_f32_32x32x16_bf16(vf0, pf0.v, o[db], 0, 0, 0);
        bf16x8 vf1 = *(const bf16x8*)(&Vs[cur][((1*4 + db)*64 + lane)*8]);
        o[db] = __builtin_amdgcn_mfma_f32_32x32x16_bf16(vf1, pf1.v, o[db], 0, 0, 0);
      }
      asm volatile("s_waitcnt lgkmcnt(0)" ::: "memory");
    }
    __builtin_amdgcn_sched_barrier(0);
    __builtin_amdgcn_s_barrier();
    cur ^= 1;
  }

  // ---- epilogue: lane holds O^T[d][q], d = 32db + 8g + 4hl + j ----
  float inv = 1.f / l_r;
  int b = bh >> 4, hh = bh & 15;
  u16* orow = ao + (size_t)(b*S_ + q)*H_ + hh*HD_;
  #pragma unroll
  for (int db = 0; db < 4; db++){
    #pragma unroll
    for (int g = 0; g < 4; g++){
      ushort4 pk4;
      pk4.x = f2bf(o[db][4*g+0]*inv);
      pk4.y = f2bf(o[db][4*g+1]*inv);
      pk4.z = f2bf(o[db][4*g+2]*inv);
      pk4.w = f2bf(o[db][4*g+3]*inv);
      *(ushort4*)(orow + db*32 + g*8 + hl*4) = pk4;
    }
  }
}

extern "C" void kernel_launch(void* const* d_in, const int* in_sizes, int n_in,
                              void* d_out, int out_size, void* d_ws, size_t ws_size,
                              hipStream_t stream) {
  const float* x      = (const float*)d_in[0];
  const float* rotary = (const float*)d_in[1];
  const float* w_qkv  = (const float*)d_in[2];
  const float* w_o    = (const float*)d_in[3];
  float* out = (float*)d_out;

  char* wsb = (char*)d_ws;
  float* part_qkv = (float*)wsb;             // [1024]
  float* part_o   = part_qkv + 1024;         // [1024]
  float* scales   = part_o + 1024;           // [2]
  size_t off = 16384;
  u16* xb    = (u16*)(wsb + off); off += (size_t)MTOK*H_*2;
  u16* wqkvq = (u16*)(wsb + off); off += (size_t)NQKV*H_*2;
  u16* woq   = (u16*)(wsb + off); off += (size_t)H_*H_*2;
  u16* qbuf  = (u16*)(wsb + off); off += (size_t)B_*NH_*S_*HD_*2;
  u16* kbuf  = (u16*)(wsb + off); off += (size_t)B_*NH_*S_*HD_*2;
  u16* vtb   = (u16*)(wsb + off); off += (size_t)B_*NH_*S_*HD_*2;
  u16* ao    = (u16*)(wsb + off); off += (size_t)MTOK*H_*2;

  absum_kernel<<<1024, 256, 0, stream>>>(w_qkv, 3*H_*H_, part_qkv);
  absum_kernel<<<1024, 256, 0, stream>>>(w_o, H_*H_, part_o);
  finalize_kernel<<<1, 256, 0, stream>>>(part_qkv, part_o, scales);
  quant_kernel<<<4096, 256, 0, stream>>>(w_qkv, wqkvq, 3*H_*H_, scales, 0);
  quant_kernel<<<2048, 256, 0, stream>>>(w_o, woq, H_*H_, scales, 1);
  castx_kernel<<<(MTOK*H_)/256, 256, 0, stream>>>(x, xb, MTOK*H_);

  gemm_kernel<0><<<(MTOK/128)*(NQKV/128), 256, 0, stream>>>(xb, wqkvq, MTOK, NQKV, H_,
                                                            nullptr, qbuf, kbuf, vtb);
  rope_kernel<<<(2*B_*NH_*S_*64)/256, 256, 0, stream>>>(qbuf, kbuf, rotary);
  attn_kernel<<<B_*NH_*(S_/128), 256, 0, stream>>>(qbuf, kbuf, vtb, ao);
  gemm_kernel<1><<<(MTOK/128)*(H_/128), 256, 0, stream>>>(ao, woq, MTOK, H_, H_,
                                                          out, nullptr, nullptr, nullptr);
}